// Round 10
// baseline (97.506 us; speedup 1.0000x reference)
//
#include <hip/hip_runtime.h>
#include <hip/hip_fp16.h>
#include <math.h>

#define NBANDS 2049
#define NF 4096      // real frame size
#define NC 2048      // complex FFT size (rfft via packed complex)
#define BUF 1024     // input samples per batch row
#define THREADS 512
#define R2C 0.70710678118654752f
#define C8  0.92387953251128674f   // cos(pi/8)
#define S8  0.38268343236508978f   // sin(pi/8)
#define C16 0.98078528040323044f   // cos(pi/16)
#define S16 0.19509032201612827f   // sin(pi/16)

// LDS swizzle: i ^ 2*((i>>5)&15). Bijective; preserves bit0 (pair adjacency,
// posrev evenness); analytically verified <= wave64-minimum banking for the
// s1 / r16a / r16b / unpack access patterns of this structure.
__device__ __forceinline__ int SWc(int i) { return i ^ (((i >> 5) & 15) << 1); }

// digit-reversed position after 5 radix-4 stages (final radix-2 folded out);
// output is always even
__device__ __forceinline__ int posrev10(int j) {
  return ((j & 3) << 9) | (((j >> 2) & 3) << 7) | (((j >> 4) & 3) << 5) |
         (((j >> 6) & 3) << 3) | (((j >> 8) & 3) << 1);
}

struct Smem {
  alignas(16) float xs[BUF];       // 4 KB
  alignas(16) float zre[4][NC];    // 32 KB
  alignas(16) float zim[4][NC];    // 32 KB
};                                 // 68 KB -> 2 blocks/CU

struct State {
  float2 W0;                     // exp(-pi i t/1024) (s1 twiddle + window base)
  float2 V;                      // exp(-2 pi i (t&31)/512) (r16a twiddle base)
  float2 Ub;                     // exp(-pi i t/2048)
  float2 U1;                     // Ub * exp(-i pi/4)
  float so;                      // sin(pi(2t+1)/2048) (odd window base)
  float s1a[5], s1b[5];          // running mins after lvl1
  float s2a[5], s2b[5];          // running mins after lvl2
  __half2 oh[4][5];              // dB output columns, f16-packed
};

__device__ __forceinline__ float2 cmul(float2 a, float2 b) {
  return make_float2(a.x * b.x - a.y * b.y, a.x * b.y + a.y * b.x);
}

template <int L>
__device__ __forceinline__ float cheb(float c) {
  #pragma unroll
  for (int i = 0; i < L; ++i) c = 2.0f * c * c - 1.0f;
  return c;
}

// Fused pack + pruned first radix-4 stage (span 512): only tap3 nonzero.
template <int L>
__device__ __forceinline__ void fused_s1(float* __restrict__ re, float* __restrict__ im,
                                         const Smem& sm, const State& st, int off) {
  const int n = threadIdx.x;
  constexpr int M = NF >> L;
  constexpr float ws = (float)(1 << L) * (0.5f / 1024.0f);
  const int lo = 512 - (min(off, M) >> 1);
  float dr = 0.0f, di = 0.0f;
  if (n >= lo) {
    const int idx = 2 * n + off - 1024;          // even, in [0, off)
    const float2 xv = *(const float2*)&sm.xs[idx];
    const float cE = cheb<L>(-st.W0.y);
    const float cO = cheb<L>(st.so);
    dr = ws * (1.0f - cE) * xv.x;
    di = ws * (1.0f - cO) * xv.y;
  }
  const float2 W = st.W0;
  const float2 W2 = make_float2(W.x * W.x - W.y * W.y, 2.0f * W.x * W.y);
  const float2 W3 = cmul(W, W2);
  const int X1 = ((n >> 5) & 15) << 1;           // SWc(n+512k) = (n+512k)^X1
  const int p0 = n ^ X1, p1 = (n + 512) ^ X1, p2 = (n + 1024) ^ X1, p3 = (n + 1536) ^ X1;
  re[p0] = dr;                       im[p0] = di;
  re[p1] = -di * W.x - dr * W.y;     im[p1] = -di * W.y + dr * W.x;     // (i d) W
  re[p2] = -(dr * W2.x - di * W2.y); im[p2] = -(dr * W2.y + di * W2.x); // -d W^2
  re[p3] =  di * W3.x + dr * W3.y;   im[p3] =  di * W3.y - dr * W3.x;   // (-i d) W^3
}

// DIF radix-4 butterfly on register slots a,b,c,d (positions q=0..3)
__device__ __forceinline__ void bflyr(float* __restrict__ xr, float* __restrict__ xi,
                                      int a, int b, int c, int d,
                                      float Wr, float Wi, float W2r, float W2i,
                                      float W3r, float W3i) {
  const float t0r = xr[a] + xr[c], t0i = xi[a] + xi[c];
  const float t1r = xr[a] - xr[c], t1i = xi[a] - xi[c];
  const float t2r = xr[b] + xr[d], t2i = xi[b] + xi[d];
  const float t3r = xr[b] - xr[d], t3i = xi[b] - xi[d];
  xr[a] = t0r + t2r; xi[a] = t0i + t2i;
  const float y1r = t1r + t3i, y1i = t1i - t3r;            // (t1 - i t3)
  xr[b] = y1r * Wr - y1i * Wi;  xi[b] = y1r * Wi + y1i * Wr;
  const float y2r = t0r - t2r, y2i = t0i - t2i;
  xr[c] = y2r * W2r - y2i * W2i; xi[c] = y2r * W2i + y2i * W2r;
  const float y3r = t1r - t3i, y3i = t1i + t3r;            // (t1 + i t3)
  xr[d] = y3r * W3r - y3i * W3i; xi[d] = y3r * W3i + y3i * W3r;
}

// radix-16 in registers: stages m=128 (twiddle V*E_s per s) and m=32 (V^4).
// Thread (c,r) owns elements {c*512 + r + 32u, u=0..15}; 128 threads/frame.
template <int NFR>
__device__ __forceinline__ void r16a(Smem& sm, const State& st) {
  const int f = threadIdx.x >> 7;
  if (f >= NFR) return;                          // wave-uniform (2 waves/frame)
  const int lt = threadIdx.x & 127;
  const int c = lt >> 5, r = lt & 31;
  const int base = c * 512 + r;                  // SWc(base+32u) = (base+32u)^(2u)
  float* __restrict__ re = sm.zre[f];
  float* __restrict__ im = sm.zim[f];
  float xr[16], xi[16];
  #pragma unroll
  for (int u = 0; u < 16; ++u) {
    const int p = (base + 32 * u) ^ (2 * u);
    xr[u] = re[p]; xi[u] = im[p];
  }
  const float ECs[4] = {1.0f, C8, R2C, S8};      // E_s = exp(-pi i s/8)
  const float ESs[4] = {0.0f, -S8, -R2C, -C8};
  #pragma unroll
  for (int s = 0; s < 4; ++s) {                  // stage m=128, u = {s,s+4,s+8,s+12}
    const float Wr = st.V.x * ECs[s] - st.V.y * ESs[s];
    const float Wi = st.V.x * ESs[s] + st.V.y * ECs[s];
    const float W2r = Wr * Wr - Wi * Wi, W2i = 2.0f * Wr * Wi;
    const float W3r = Wr * W2r - Wi * W2i, W3i = Wr * W2i + Wi * W2r;
    bflyr(xr, xi, s, s + 4, s + 8, s + 12, Wr, Wi, W2r, W2i, W3r, W3i);
  }
  const float sqr = st.V.x * st.V.x - st.V.y * st.V.y, sqi = 2.0f * st.V.x * st.V.y;
  const float Tr = sqr * sqr - sqi * sqi, Ti = 2.0f * sqr * sqi;       // V^4
  const float T2r = Tr * Tr - Ti * Ti, T2i = 2.0f * Tr * Ti;
  const float T3r = Tr * T2r - Ti * T2i, T3i = Tr * T2i + Ti * T2r;
  #pragma unroll
  for (int b = 0; b < 4; ++b)                    // stage m=32, u = {4b..4b+3}
    bflyr(xr, xi, 4 * b, 4 * b + 1, 4 * b + 2, 4 * b + 3, Tr, Ti, T2r, T2i, T3r, T3i);
  #pragma unroll
  for (int u = 0; u < 16; ++u) {
    const int p = (base + 32 * u) ^ (2 * u);
    re[p] = xr[u]; im[p] = xi[u];
  }
}

// radix-16 in registers: stages m=8 and m=2 — all twiddles are constants by r2.
// Thread (c2,r2) owns elements {c2*32 + r2 + 2u, u=0..15}.
template <int NFR>
__device__ __forceinline__ void r16b(Smem& sm) {
  const int f = threadIdx.x >> 7;
  if (f >= NFR) return;
  const int lt = threadIdx.x & 127;
  const int c2 = lt >> 1, r2 = lt & 1;
  const int base = c2 * 32 + r2;
  const int X = (c2 & 15) << 1;                  // SWc(base+2u) = (base+2u)^X
  float* __restrict__ re = sm.zre[f];
  float* __restrict__ im = sm.zim[f];
  float xr[16], xi[16];
  #pragma unroll
  for (int u = 0; u < 16; ++u) {
    const int p = (base + 2 * u) ^ X;
    xr[u] = re[p]; xi[u] = im[p];
  }
  const float v2r = r2 ? C16 : 1.0f;             // V2 = exp(-pi i r2/16)
  const float v2i = r2 ? -S16 : 0.0f;
  const float ECs[4] = {1.0f, C8, R2C, S8};
  const float ESs[4] = {0.0f, -S8, -R2C, -C8};
  #pragma unroll
  for (int s = 0; s < 4; ++s) {                  // stage m=8
    const float Wr = v2r * ECs[s] - v2i * ESs[s];
    const float Wi = v2r * ESs[s] + v2i * ECs[s];
    const float W2r = Wr * Wr - Wi * Wi, W2i = 2.0f * Wr * Wi;
    const float W3r = Wr * W2r - Wi * W2i, W3i = Wr * W2i + Wi * W2r;
    bflyr(xr, xi, s, s + 4, s + 8, s + 12, Wr, Wi, W2r, W2i, W3r, W3i);
  }
  const float Tr = r2 ? R2C : 1.0f, Ti = r2 ? -R2C : 0.0f;   // exp(-pi i r2/4)
  const float T2r = r2 ? 0.0f : 1.0f, T2i = r2 ? -1.0f : 0.0f;
  const float T3r = r2 ? -R2C : 1.0f, T3i = r2 ? -R2C : 0.0f;
  #pragma unroll
  for (int b = 0; b < 4; ++b)                    // stage m=2
    bflyr(xr, xi, 4 * b, 4 * b + 1, 4 * b + 2, 4 * b + 3, Tr, Ti, T2r, T2i, T3r, T3i);
  #pragma unroll
  for (int u = 0; u < 16; ++u) {
    const int p = (base + 2 * u) ^ X;
    re[p] = xr[u]; im[p] = xi[u];
  }
}

// Shared-read pair unpack; q's are even under SWc so {q,q+1} is one float2.
__device__ __forceinline__ void pair_powers(const float* __restrict__ re,
                                            const float* __restrict__ im,
                                            int kp, float2 U, float& pp, float& pm) {
  const int k1 = kp & (NC - 1);
  const int k2 = (NC - kp) & (NC - 1);
  const int q1 = SWc(posrev10(k1 & 1023));   // even
  const int q2 = SWc(posrev10(k2 & 1023));   // even
  const float s1 = (k1 & 1024) ? -1.0f : 1.0f;
  const float s2 = (k2 & 1024) ? -1.0f : 1.0f;
  const float2 vr1 = *(const float2*)&re[q1];
  const float2 vi1 = *(const float2*)&im[q1];
  const float2 vr2 = *(const float2*)&re[q2];
  const float2 vi2 = *(const float2*)&im[q2];
  const float zkr = vr1.x + s1 * vr1.y;
  const float zki = vi1.x + s1 * vi1.y;
  const float zmr = vr2.x + s2 * vr2.y;
  const float zmi = vi2.x + s2 * vi2.y;
  const float Ex = 0.5f * (zkr + zmr), Ey = 0.5f * (zki - zmi);
  const float Ox = 0.5f * (zki + zmi), Oy = -0.5f * (zkr - zmr);
  const float Vx = U.x * Ox - U.y * Oy, Vy = U.x * Oy + U.y * Ox;
  const float ax = Ex + Vx, ay = Ey + Vy;
  const float bx = Ex - Vx, by = Ey - Vy;
  pp = ax * ax + ay * ay;
  pm = bx * bx + by * by;
}

// ACT: 0 s1a=min(p,1e6); 1 s1b=min(p,1e6); 2 lvl0 fold into s1a&s1b;
//      3 s2a=min(s1a,p); 4 s2b=min(s1a,p); 5 s2a=min(s1b,p); 6 s2b=min(s1b,p);
//      7 o[COL]=dB(min(s2a,p)); 8 o[COL]=dB(min(s2b,p))
template <int ACT, int COL, int SLOT>
__device__ __forceinline__ void act(State& st, float p) {
  if constexpr (ACT == 0)      st.s1a[SLOT] = fminf(p, 1.0e6f);
  else if constexpr (ACT == 1) st.s1b[SLOT] = fminf(p, 1.0e6f);
  else if constexpr (ACT == 2) { st.s1a[SLOT] = fminf(st.s1a[SLOT], p); st.s1b[SLOT] = fminf(st.s1b[SLOT], p); }
  else if constexpr (ACT == 3) st.s2a[SLOT] = fminf(st.s1a[SLOT], p);
  else if constexpr (ACT == 4) st.s2b[SLOT] = fminf(st.s1a[SLOT], p);
  else if constexpr (ACT == 5) st.s2a[SLOT] = fminf(st.s1b[SLOT], p);
  else if constexpr (ACT == 6) st.s2b[SLOT] = fminf(st.s1b[SLOT], p);
  else {
    const float base = (ACT == 7) ? st.s2a[SLOT] : st.s2b[SLOT];
    const float db = 10.0f * log10f(fmaxf(fminf(base, p), 1.0e-10f));
    if constexpr (COL & 1) st.oh[COL >> 1][SLOT].y = __float2half_rn(db);
    else                   st.oh[COL >> 1][SLOT].x = __float2half_rn(db);
  }
}

template <int ACT, int COL>
__device__ __forceinline__ void unpack_frame(const float* __restrict__ re,
                                             const float* __restrict__ im,
                                             State& st) {
  const int t = threadIdx.x;
  float pp, pm;
  pair_powers(re, im, t, st.Ub, pp, pm);
  act<ACT, COL, 0>(st, pp);
  act<ACT, COL, 1>(st, pm);
  pair_powers(re, im, 512 + t, st.U1, pp, pm);
  act<ACT, COL, 2>(st, pp);
  act<ACT, COL, 3>(st, pm);
  if (t == 0) {
    const float zr = re[0] - re[1];              // bin 1024: Z = D[0]-D[1]
    const float zi = im[0] - im[1];
    act<ACT, COL, 4>(st, zr * zr + zi * zi);
  }
}

// One pass = up to four windowed frames FFT'd together.
template <int LA, int AA, int CA, int LB, int AB, int CB,
          int LC, int AC, int CC, int LD, int AD, int CD, int NFR>
__device__ __forceinline__ void pass(Smem& sm, State& st,
                                     int offA, int offB, int offC, int offD) {
  __syncthreads();                               // prior unpack done with z
  fused_s1<LA>(sm.zre[0], sm.zim[0], sm, st, offA);
  if constexpr (NFR >= 2) fused_s1<LB>(sm.zre[1], sm.zim[1], sm, st, offB);
  if constexpr (NFR >= 3) fused_s1<LC>(sm.zre[2], sm.zim[2], sm, st, offC);
  if constexpr (NFR >= 4) fused_s1<LD>(sm.zre[3], sm.zim[3], sm, st, offD);
  __syncthreads();
  r16a<NFR>(sm, st);
  __syncthreads();
  r16b<NFR>(sm);
  __syncthreads();
  unpack_frame<AA, CA>(sm.zre[0], sm.zim[0], st);
  if constexpr (NFR >= 2) unpack_frame<AB, CB>(sm.zre[1], sm.zim[1], st);
  if constexpr (NFR >= 3) unpack_frame<AC, CC>(sm.zre[2], sm.zim[2], st);
  if constexpr (NFR >= 4) unpack_frame<AD, CD>(sm.zre[3], sm.zim[3], st);
}

// Thread t owns bands {t, 2048-t, 512+t, 1536-t, (1024 if t==0)}; 32B per band.
__device__ __forceinline__ void store_all(const State& st, float* __restrict__ outb) {
  const int t = threadIdx.x;
  #pragma unroll
  for (int sl = 0; sl < 5; ++sl) {
    if (sl < 4 || t == 0) {
      const int band = (sl == 0) ? t : (sl == 1) ? 2048 - t
                     : (sl == 2) ? 512 + t : (sl == 3) ? 1536 - t : 1024;
      float* bp = outb + (size_t)band * 8;
      *(float4*)(bp)     = make_float4(__half2float(st.oh[0][sl].x), __half2float(st.oh[0][sl].y),
                                       __half2float(st.oh[1][sl].x), __half2float(st.oh[1][sl].y));
      *(float4*)(bp + 4) = make_float4(__half2float(st.oh[2][sl].x), __half2float(st.oh[2][sl].y),
                                       __half2float(st.oh[3][sl].x), __half2float(st.oh[3][sl].y));
    }
  }
}

__global__ __launch_bounds__(THREADS, 2) void spec_kernel(const float* __restrict__ x,
                                                          float* __restrict__ out) {
  __shared__ Smem sm;
  State st;
  const int tid = threadIdx.x;
  const int b = blockIdx.x;
  const float* xb = x + (size_t)b * BUF;
  #pragma unroll
  for (int i = tid; i < BUF; i += THREADS) sm.xs[i] = xb[i];
  {
    float sn, cs;
    sincospif((float)tid * (1.0f / 1024.0f), &sn, &cs);           st.W0 = make_float2(cs, -sn);
    sincospif((float)(tid & 31) * (1.0f / 256.0f), &sn, &cs);     st.V  = make_float2(cs, -sn);
    sincospif((float)tid * (1.0f / 2048.0f), &sn, &cs);           st.Ub = make_float2(cs, -sn);
    st.U1 = cmul(st.Ub, make_float2(R2C, -R2C));
    sincospif((float)(2 * tid + 1) * (1.0f / 2048.0f), &sn, &cs); st.so = sn;
  }
  float* outb = out + (size_t)b * (NBANDS * 8);

  // Frames: l0 off=1024; l1_i off=512(i+1); l2_i off=256(i+1); l3_i off=128(i+1).
  // 15 frames in 4 passes (4+4+4+3); unpack order A,B,C,D respects min-chain RAW.
  pass<1, 0, 0,  1, 1, 0,  0, 2, 0,  2, 3, 0, 4>(sm, st, 512, 1024, 1024, 256);
  pass<2, 4, 0,  3, 7, 0,  3, 7, 1,  2, 5, 0, 4>(sm, st, 512, 128, 256, 768);
  pass<3, 8, 2,  3, 8, 3,  2, 6, 0,  3, 7, 4, 4>(sm, st, 384, 512, 1024, 640);
  pass<3, 7, 5,  3, 8, 6,  3, 8, 7,  0, 0, 0, 3>(sm, st, 768, 896, 1024, 0);
  store_all(st, outb);
}

extern "C" void kernel_launch(void* const* d_in, const int* in_sizes, int n_in,
                              void* d_out, int out_size, void* d_ws, size_t ws_size,
                              hipStream_t stream) {
  const float* x = (const float*)d_in[0];
  float* out = (float*)d_out;
  const int B = in_sizes[0] / BUF;
  hipLaunchKernelGGL(spec_kernel, dim3(B), dim3(THREADS), 0, stream, x, out);
}